// Round 1
// baseline (553.781 us; speedup 1.0000x reference)
//
#include <hip/hip_runtime.h>
#include <hip/hip_bf16.h>
#include <cstdint>
#include <cstddef>

#define T_DIM 2048
#define B_DIM 32
#define D_DIM 512
#define H_DIM 768
#define C_DIM 10
#define K_DIM D_DIM             /* 512  */
#define N_DIM (4 * H_DIM)       /* 3072 */

#define TC 1024                 /* timesteps per chunk */
#define NCHUNK (T_DIM / TC)     /* 2 */
#define MC (TC * B_DIM)         /* 32768 rows per chunk GEMM */

#define L_SEG 64                /* scan segment length */
#define S_SEG (TC / L_SEG)      /* 16 segments per chunk */
#define BH (B_DIM * H_DIM)      /* 24576 chains */

typedef __attribute__((ext_vector_type(8))) short short8;
typedef __attribute__((ext_vector_type(4))) float float4v;

__device__ inline unsigned short f2bf(float f) {
  unsigned int u = __builtin_bit_cast(unsigned int, f);
  unsigned int r = (u + 0x7FFFu + ((u >> 16) & 1u)) >> 16;
  return (unsigned short)r;
}
__device__ inline float bf2f(unsigned short s) {
  unsigned int u = ((unsigned int)s) << 16;
  return __builtin_bit_cast(float, u);
}
__device__ inline float fast_rcp(float x) { return __builtin_amdgcn_rcpf(x); }
__device__ inline float fast_exp2(float x) { return __builtin_amdgcn_exp2f(x); }
__device__ inline float sigmoid_f(float x) {
  float e = fast_exp2(-1.4426950408889634f * x);
  return fast_rcp(1.0f + e);
}
__device__ inline float tanh_f(float x) {
  float e = fast_exp2(2.885390081777927f * x);
  return 1.0f - 2.0f * fast_rcp(e + 1.0f);
}
__device__ inline void gld16(const unsigned short* g, unsigned short* l) {
  __builtin_amdgcn_global_load_lds(
      (const __attribute__((address_space(1))) void*)g,
      (__attribute__((address_space(3))) void*)l, 16, 0, 0);
}
__device__ inline unsigned int pack_bf16x2(float lo, float hi) {
  return ((unsigned int)f2bf(hi) << 16) | (unsigned int)f2bf(lo);
}

// ---------------------------------------------------------------------------
// Kernel 1: chunked embedding gather + fp32->bf16
// ---------------------------------------------------------------------------
__global__ __launch_bounds__(256) void gather_embed_kernel(
    const int* __restrict__ x_c, const float* __restrict__ table,
    unsigned short* __restrict__ ebfc) {
  int idx = blockIdx.x * 256 + threadIdx.x;
  int m = idx >> 7;
  int k4 = (idx & 127) << 2;
  int row = x_c[m];
  float4 v = *(const float4*)(table + (size_t)row * D_DIM + k4);
  ushort4 o;
  o.x = f2bf(v.x); o.y = f2bf(v.y); o.z = f2bf(v.z); o.w = f2bf(v.w);
  *(ushort4*)(ebfc + (size_t)m * D_DIM + k4) = o;
}

// ---------------------------------------------------------------------------
// Kernel 2: concat 4 weight matrices -> bf16  wcat[n][k], n: [Wx;Wf;Wr;Wcx]
// ---------------------------------------------------------------------------
__global__ __launch_bounds__(256) void convert_w_kernel(
    const float* __restrict__ Wx, const float* __restrict__ Wf,
    const float* __restrict__ Wr, const float* __restrict__ Wcx,
    unsigned short* __restrict__ wcat) {
  int idx = blockIdx.x * 256 + threadIdx.x;
  int n = idx >> 7;
  int k4 = (idx & 127) << 2;
  int mat = n / H_DIM;
  int h = n - mat * H_DIM;
  const float* src = (mat == 0) ? Wx : (mat == 1) ? Wf : (mat == 2) ? Wr : Wcx;
  float4 v = *(const float4*)(src + (size_t)h * D_DIM + k4);
  ushort4 o;
  o.x = f2bf(v.x); o.y = f2bf(v.y); o.z = f2bf(v.z); o.w = f2bf(v.w);
  *(ushort4*)(wcat + (size_t)n * D_DIM + k4) = o;
}

// ---------------------------------------------------------------------------
// Kernel 3: 256x256-tile 8-phase bf16 MFMA GEMM (T2+T3+T4+T5 per the proven
// 256^2 8-phase template).
//   - 512 threads = 8 waves, 2 (n-half) x 4 (m-quarter); wave tile 128n x 64m
//   - BK=64, K=512 -> 8 K-tiles; 2x double-buffered LDS: 4 half-tiles of
//     16 KB each (A0,A1,B0,B1) per buffer = 128 KiB total
//   - per K-tile 4 phases: {ds_read subtile | stage 1 half-tile -> raw
//     s_barrier -> setprio(1) -> 16 MFMA -> setprio(0) -> barrier}
//   - stage schedule: P1:A0(u+1) P2:A1(u+1) P3:B0(u+2) P4:B1(u+2)
//     (B regions of the READ buffer free after P2 -> B prefetches 2 tiles deep)
//   - ONE counted wait per K-tile: s_waitcnt vmcnt(4) at P4 end; 2 half-tiles
//     (4 loads/thread) stay in flight across every barrier. NEVER vmcnt(0)
//     in the main loop (tiles 6,7 peeled: vmcnt(0)/no-stage tail).
//   - LDS swizzle: phys 16B chunk = logical ^ (row&7), applied on the
//     global SOURCE address (gload_lds dest must stay linear) and on ds_read.
//   - epilogue: bias/sigmoid -> swizzled LDS transpose (fills the full
//     128 KB after the last barrier) -> perfectly coalesced 16B stores.
// ---------------------------------------------------------------------------
#define BMT 256
#define BNT 256
#define BKT 64
#define NTILES (K_DIM / BKT)    /* 8 */

__device__ __forceinline__ float4v mfma16(short8 a, short8 b, float4v c) {
  return __builtin_amdgcn_mfma_f32_16x16x32_bf16(a, b, c, 0, 0, 0);
}

// stage half h (128 rows) of matrix (isB: ebfc else wcat) K-tile kt into
// buffer parity pb.  2 x global_load_lds(16B) per thread.
__device__ __forceinline__ void stg(const unsigned short* src, unsigned short* sm,
                                    int pb, int isB, int h, int kt, int tid) {
  const unsigned short* s = src + (size_t)(h * 128) * K_DIM + kt * BKT;
  unsigned short* d = sm + pb * 32768 + isB * 16384 + h * 8192 + tid * 8;
  gld16(s, d);
  gld16(s + (size_t)64 * K_DIM, d + 4096);
}

template <int S1, int S2, int S3, int S4, int VMN>
__device__ __forceinline__ void tile_step(
    int u, unsigned short* sm, const unsigned short* srcA,
    const unsigned short* srcB, int tid, int aO, int bO, int c0, int c1,
    float4v (&acc)[8][4]) {
  const int pb = u & 1, pn = pb ^ 1;
  const int ab = pb * 32768 + aO;
  const int bb = pb * 32768 + bO;
  short8 a[4][2], b0[2][2], b1[2][2];

  // ---- phase 1: read A n-quad0 (8) + B m-quad0 (4); stage A0(u+1) ----
#pragma unroll
  for (int f = 0; f < 4; f++) {
    a[f][0] = *(const short8*)(sm + ab + f * 1024 + c0);
    a[f][1] = *(const short8*)(sm + ab + f * 1024 + c1);
  }
#pragma unroll
  for (int g = 0; g < 2; g++) {
    b0[g][0] = *(const short8*)(sm + bb + g * 1024 + c0);
    b0[g][1] = *(const short8*)(sm + bb + g * 1024 + c1);
  }
  if constexpr (S1) stg(srcA, sm, pn, 0, 0, u + 1, tid);
  __builtin_amdgcn_sched_barrier(0);
  __builtin_amdgcn_s_barrier();
  __builtin_amdgcn_s_setprio(1);
#pragma unroll
  for (int f = 0; f < 4; f++)
#pragma unroll
    for (int g = 0; g < 2; g++) {
      acc[f][g] = mfma16(a[f][0], b0[g][0], acc[f][g]);
      acc[f][g] = mfma16(a[f][1], b0[g][1], acc[f][g]);
    }
  __builtin_amdgcn_s_setprio(0);
  __builtin_amdgcn_sched_barrier(0);
  __builtin_amdgcn_s_barrier();

  // ---- phase 2: read B m-quad1 (4); stage A1(u+1) ----
#pragma unroll
  for (int g = 0; g < 2; g++) {
    b1[g][0] = *(const short8*)(sm + bb + 2048 + g * 1024 + c0);
    b1[g][1] = *(const short8*)(sm + bb + 2048 + g * 1024 + c1);
  }
  if constexpr (S2) stg(srcA, sm, pn, 0, 1, u + 1, tid);
  __builtin_amdgcn_sched_barrier(0);
  __builtin_amdgcn_s_barrier();
  __builtin_amdgcn_s_setprio(1);
#pragma unroll
  for (int f = 0; f < 4; f++)
#pragma unroll
    for (int g = 0; g < 2; g++) {
      acc[f][2 + g] = mfma16(a[f][0], b1[g][0], acc[f][2 + g]);
      acc[f][2 + g] = mfma16(a[f][1], b1[g][1], acc[f][2 + g]);
    }
  __builtin_amdgcn_s_setprio(0);
  __builtin_amdgcn_sched_barrier(0);
  __builtin_amdgcn_s_barrier();

  // ---- phase 3: read A n-quad1 (8); stage B0(u+2) into READ buffer ----
#pragma unroll
  for (int f = 0; f < 4; f++) {
    a[f][0] = *(const short8*)(sm + ab + 4096 + f * 1024 + c0);
    a[f][1] = *(const short8*)(sm + ab + 4096 + f * 1024 + c1);
  }
  if constexpr (S3) stg(srcB, sm, pb, 1, 0, u + 2, tid);
  __builtin_amdgcn_sched_barrier(0);
  __builtin_amdgcn_s_barrier();
  __builtin_amdgcn_s_setprio(1);
#pragma unroll
  for (int f = 0; f < 4; f++)
#pragma unroll
    for (int g = 0; g < 2; g++) {
      acc[4 + f][2 + g] = mfma16(a[f][0], b1[g][0], acc[4 + f][2 + g]);
      acc[4 + f][2 + g] = mfma16(a[f][1], b1[g][1], acc[4 + f][2 + g]);
    }
  __builtin_amdgcn_s_setprio(0);
  __builtin_amdgcn_sched_barrier(0);
  __builtin_amdgcn_s_barrier();

  // ---- phase 4: no reads (b0 live since P1); stage B1(u+2); counted wait ----
  if constexpr (S4) stg(srcB, sm, pb, 1, 1, u + 2, tid);
  __builtin_amdgcn_sched_barrier(0);
  __builtin_amdgcn_s_barrier();
  __builtin_amdgcn_s_setprio(1);
#pragma unroll
  for (int f = 0; f < 4; f++)
#pragma unroll
    for (int g = 0; g < 2; g++) {
      acc[4 + f][g] = mfma16(a[f][0], b0[g][0], acc[4 + f][g]);
      acc[4 + f][g] = mfma16(a[f][1], b0[g][1], acc[4 + f][g]);
    }
  __builtin_amdgcn_s_setprio(0);
  __builtin_amdgcn_sched_barrier(0);
  if constexpr (VMN == 4)
    asm volatile("s_waitcnt vmcnt(4)" ::: "memory");
  else if constexpr (VMN == 0)
    asm volatile("s_waitcnt vmcnt(0)" ::: "memory");
  __builtin_amdgcn_s_barrier();
}

__global__ __launch_bounds__(512, 2) void gemm_kernel(
    const unsigned short* __restrict__ ebfc,
    const unsigned short* __restrict__ wcat,
    const float* __restrict__ b_f, const float* __restrict__ b_r,
    const float* __restrict__ b_cx,
    unsigned short* __restrict__ projc) {
  __shared__ __align__(16) unsigned short smem[65536];  // 128 KB

  const int tid = threadIdx.x;
  const int wave = tid >> 6;
  const int lane = tid & 63;
  const int quad = lane >> 4;
  const int l16 = lane & 15;
  const int wn = wave >> 2;   // n half of A tile (128 rows)
  const int wm = wave & 3;    // m quarter of B tile (64 rows)

  const int n0 = blockIdx.x * BNT;
  const int m0 = blockIdx.y * BMT;

  // staging source: row (tid>>3), swizzled k-chunk (tid&7)^(row&7)
  const int srow = tid >> 3;
  const int kch = (tid & 7) ^ (srow & 7);
  const unsigned short* srcA = wcat + (size_t)(n0 + srow) * K_DIM + kch * 8;
  const unsigned short* srcB = ebfc + (size_t)(m0 + srow) * K_DIM + kch * 8;

  // ds_read lane bases (ushort units); chunk term per k-step
  const int aO = wn * 8192 + l16 * 64;
  const int bO = 16384 + (wm >> 1) * 8192 + (wm & 1) * 4096 + l16 * 64;
  const int c0 = (quad ^ (lane & 7)) * 8;
  const int c1 = ((quad ^ (lane & 7)) ^ 4) * 8;

  float4v acc[8][4] = {};

  // ---- prologue: tile0 all 4 halves + tile1 B halves; counted wait ----
  stg(srcB, smem, 0, 1, 0, 0, tid);
  stg(srcB, smem, 0, 1, 1, 0, tid);
  stg(srcA, smem, 0, 0, 0, 0, tid);
  stg(srcA, smem, 0, 0, 1, 0, tid);
  stg(srcB, smem, 1, 1, 0, 1, tid);
  stg(srcB, smem, 1, 1, 1, 1, tid);
  asm volatile("s_waitcnt vmcnt(4)" ::: "memory");
  __builtin_amdgcn_s_barrier();

  // ---- main loop: steady 8-phase schedule, vmcnt(4) per K-tile ----
#pragma unroll 2
  for (int u = 0; u < NTILES - 2; u++)
    tile_step<1, 1, 1, 1, 4>(u, smem, srcA, srcB, tid, aO, bO, c0, c1, acc);
  // ---- peeled tail: no OOB stages; drain before last tile ----
  tile_step<1, 1, 0, 0, 0>(NTILES - 2, smem, srcA, srcB, tid, aO, bO, c0, c1, acc);
  tile_step<0, 0, 0, 0, -1>(NTILES - 1, smem, srcA, srcB, tid, aO, bO, c0, c1, acc);

  // ---- epilogue: bias/sigmoid -> swizzled LDS transpose -> 16B stores ----
  int mat = n0 / H_DIM;                      // uniform per block (768 = 3*256)
  int hb = n0 - mat * H_DIM;
  size_t matBase = (size_t)mat * MC * H_DIM;
  const float* bias = (mat == 1) ? b_f : (mat == 2) ? b_r : b_cx;
#pragma unroll
  for (int f = 0; f < 8; f++) {
    int hl = wn * 128 + f * 16 + quad * 4;   // local h, 4 consecutive
    float4 bv;
    if (mat == 0) { bv.x = bv.y = bv.z = bv.w = 0.0f; }
    else          { bv = *(const float4*)(bias + hb + hl); }
#pragma unroll
    for (int g = 0; g < 4; g++) {
      int ml = wm * 64 + g * 16 + l16;       // local m
      float v0 = acc[f][g][0] + bv.x;
      float v1 = acc[f][g][1] + bv.y;
      float v2 = acc[f][g][2] + bv.z;
      float v3 = acc[f][g][3] + bv.w;
      if (mat == 1 || mat == 2) {
        v0 = sigmoid_f(v0); v1 = sigmoid_f(v1);
        v2 = sigmoid_f(v2); v3 = sigmoid_f(v3);
      }
      uint2 pk;
      pk.x = pack_bf16x2(v0, v1);
      pk.y = pack_bf16x2(v2, v3);
      int log8 = hl >> 2;                    // 8-byte chunk of h row
      int phys8 = log8 ^ ((ml & 7) << 1);    // even XOR: 16B pairs stay adjacent
      *(uint2*)(smem + ml * 256 + phys8 * 4) = pk;
    }
  }
  __syncthreads();
#pragma unroll
  for (int it = 0; it < 16; it++) {
    int idx = it * 512 + tid;
    int ml = idx >> 5;
    int c16 = idx & 31;
    int phys16 = c16 ^ (ml & 7);
    short8 v = *(const short8*)(smem + ml * 256 + phys16 * 8);
    *(short8*)(projc + matBase + (size_t)(m0 + ml) * H_DIM + hb + c16 * 8) = v;
  }
}

// ---------------------------------------------------------------------------
// Kernel 4a (scan1): per-segment summaries P = prod f, Q = c_out given c_in=0.
// ---------------------------------------------------------------------------
__global__ __launch_bounds__(128) void scan1_kernel(
    const unsigned short* __restrict__ projc,
    float* __restrict__ Pw, float* __restrict__ Qw) {
  int blk = blockIdx.x;
  int seg = blk / (BH / 512);
  int q   = blk % (BH / 512);
  int e4  = (q * 128 + threadIdx.x) * 4;
  const size_t mstr = (size_t)MC * H_DIM;
  size_t idx0 = (size_t)(seg * L_SEG) * BH + e4;
  float p0 = 1.f, p1 = 1.f, p2 = 1.f, p3 = 1.f;
  float c0 = 0.f, c1 = 0.f, c2 = 0.f, c3 = 0.f;
#pragma unroll 4
  for (int t = 0; t < L_SEG; t++) {
    size_t id = idx0 + (size_t)t * BH;
    ushort4 xp = *(const ushort4*)(projc + id);
    ushort4 ff = *(const ushort4*)(projc + mstr + id);
    float f0 = bf2f(ff.x), f1 = bf2f(ff.y), f2 = bf2f(ff.z), f3 = bf2f(ff.w);
    c0 = fmaf(f0, c0 - bf2f(xp.x), bf2f(xp.x));
    c1 = fmaf(f1, c1 - bf2f(xp.y), bf2f(xp.y));
    c2 = fmaf(f2, c2 - bf2f(xp.z), bf2f(xp.z));
    c3 = fmaf(f3, c3 - bf2f(xp.w), bf2f(xp.w));
    p0 *= f0; p1 *= f1; p2 *= f2; p3 *= f3;
  }
  int o = seg * BH + e4;
  *(float4*)(Pw + o) = make_float4(p0, p1, p2, p3);
  *(float4*)(Qw + o) = make_float4(c0, c1, c2, c3);
}

// ---------------------------------------------------------------------------
// Kernel 4b (prefix): chain segments exactly: c_out = P*c_in + Q.
// ---------------------------------------------------------------------------
__global__ __launch_bounds__(256) void prefix_kernel(
    const float* __restrict__ Pw, const float* __restrict__ Qw,
    float* __restrict__ cin, float* __restrict__ c_state,
    const float* __restrict__ segmax, float* __restrict__ hm_state,
    int first, int hm_init) {
  int gid = blockIdx.x * 256 + threadIdx.x;
  float c = first ? 0.f : c_state[gid];
#pragma unroll
  for (int s = 0; s < S_SEG; s++) {
    cin[s * BH + gid] = c;
    c = fmaf(Pw[s * BH + gid], c, Qw[s * BH + gid]);
  }
  c_state[gid] = c;
  if (!first) {
    float m = segmax[gid];
#pragma unroll
    for (int s = 1; s < S_SEG; s++) m = fmaxf(m, segmax[s * BH + gid]);
    hm_state[gid] = hm_init ? m : fmaxf(hm_state[gid], m);
  }
}

// ---------------------------------------------------------------------------
// Kernel 4c (scan2): replay each segment from true c_in; h + segment max.
// ---------------------------------------------------------------------------
__global__ __launch_bounds__(128) void scan2_kernel(
    const unsigned short* __restrict__ projc,
    const float* __restrict__ cin, float* __restrict__ segmax) {
  int blk = blockIdx.x;
  int seg = blk / (BH / 512);
  int q   = blk % (BH / 512);
  int e4  = (q * 128 + threadIdx.x) * 4;
  const size_t mstr = (size_t)MC * H_DIM;
  size_t idx0 = (size_t)(seg * L_SEG) * BH + e4;
  int o = seg * BH + e4;
  float4 cv = *(const float4*)(cin + o);
  float c0 = cv.x, c1 = cv.y, c2 = cv.z, c3 = cv.w;
  float m0 = -1e30f, m1 = -1e30f, m2 = -1e30f, m3 = -1e30f;
#pragma unroll 2
  for (int t = 0; t < L_SEG; t++) {
    size_t id = idx0 + (size_t)t * BH;
    ushort4 xp = *(const ushort4*)(projc + id);
    ushort4 ff = *(const ushort4*)(projc + mstr + id);
    ushort4 rr = *(const ushort4*)(projc + 2 * mstr + id);
    ushort4 cx = *(const ushort4*)(projc + 3 * mstr + id);
    c0 = fmaf(bf2f(ff.x), c0 - bf2f(xp.x), bf2f(xp.x));
    c1 = fmaf(bf2f(ff.y), c1 - bf2f(xp.y), bf2f(xp.y));
    c2 = fmaf(bf2f(ff.z), c2 - bf2f(xp.z), bf2f(xp.z));
    c3 = fmaf(bf2f(ff.w), c3 - bf2f(xp.w), bf2f(xp.w));
    float h0 = fmaf(bf2f(rr.x), tanh_f(c0) - bf2f(cx.x), bf2f(cx.x));
    float h1 = fmaf(bf2f(rr.y), tanh_f(c1) - bf2f(cx.y), bf2f(cx.y));
    float h2 = fmaf(bf2f(rr.z), tanh_f(c2) - bf2f(cx.z), bf2f(cx.z));
    float h3 = fmaf(bf2f(rr.w), tanh_f(c3) - bf2f(cx.w), bf2f(cx.w));
    m0 = fmaxf(m0, h0); m1 = fmaxf(m1, h1);
    m2 = fmaxf(m2, h2); m3 = fmaxf(m3, h3);
  }
  *(float4*)(segmax + o) = make_float4(m0, m1, m2, m3);
}

// ---------------------------------------------------------------------------
// Kernel 4d: final pool = tanh(tanh(max(hm_state, last chunk's segmax)))
// ---------------------------------------------------------------------------
__global__ __launch_bounds__(256) void pool_final_kernel(
    const float* __restrict__ segmax, const float* __restrict__ hm_state,
    float* __restrict__ pooled) {
  int gid = blockIdx.x * 256 + threadIdx.x;
  float m = hm_state[gid];
#pragma unroll
  for (int s = 0; s < S_SEG; s++) m = fmaxf(m, segmax[s * BH + gid]);
  pooled[gid] = tanh_f(tanh_f(m));
}

// ---------------------------------------------------------------------------
// Kernel 5: classifier  logit[b][c] = pooled[b]·W_out[c] + b_out[c]
// ---------------------------------------------------------------------------
__global__ __launch_bounds__(64) void classifier_kernel(
    const float* __restrict__ pooled, const float* __restrict__ W_out,
    const float* __restrict__ b_out, float* __restrict__ out) {
  int b = blockIdx.x / C_DIM;
  int c = blockIdx.x % C_DIM;
  int lane = threadIdx.x;
  float s = 0.0f;
#pragma unroll
  for (int i = 0; i < H_DIM / 64; i++) {
    int h = i * 64 + lane;
    s += pooled[(size_t)b * H_DIM + h] * W_out[(size_t)c * H_DIM + h];
  }
#pragma unroll
  for (int off = 32; off; off >>= 1) s += __shfl_down(s, off, 64);
  if (lane == 0) out[b * C_DIM + c] = s + b_out[c];
}

// ---------------------------------------------------------------------------
extern "C" void kernel_launch(void* const* d_in, const int* in_sizes, int n_in,
                              void* d_out, int out_size, void* d_ws, size_t ws_size,
                              hipStream_t stream) {
  const int*   x     = (const int*)d_in[0];
  const float* table = (const float*)d_in[1];
  const float* W_x   = (const float*)d_in[2];
  const float* W_f   = (const float*)d_in[3];
  const float* b_f   = (const float*)d_in[4];
  const float* W_r   = (const float*)d_in[5];
  const float* b_r   = (const float*)d_in[6];
  const float* W_cx  = (const float*)d_in[7];
  const float* b_cx  = (const float*)d_in[8];
  const float* W_out = (const float*)d_in[9];
  const float* b_out = (const float*)d_in[10];

  // workspace layout (~245 MB; ws_size ~411 MB per harness fill size)
  char* ws = (char*)d_ws;
  size_t off = 0;
  unsigned short* wcat  = (unsigned short*)(ws + off); off += (size_t)N_DIM * K_DIM * 2;
  unsigned short* ebfc  = (unsigned short*)(ws + off); off += (size_t)MC * K_DIM * 2;
  unsigned short* projc = (unsigned short*)(ws + off); off += (size_t)4 * MC * H_DIM * 2;
  float* Pw     = (float*)(ws + off); off += (size_t)S_SEG * BH * 4;
  float* Qw     = (float*)(ws + off); off += (size_t)S_SEG * BH * 4;
  float* cin    = (float*)(ws + off); off += (size_t)S_SEG * BH * 4;
  float* segmax = (float*)(ws + off); off += (size_t)S_SEG * BH * 4;
  float* c_st   = (float*)(ws + off); off += (size_t)BH * 4;
  float* hm_st  = (float*)(ws + off); off += (size_t)BH * 4;
  float* pooled = (float*)(ws + off); off += (size_t)BH * 4;

  convert_w_kernel<<<(N_DIM * K_DIM / 4) / 256, 256, 0, stream>>>(W_x, W_f, W_r, W_cx, wcat);

  dim3 g(N_DIM / BNT, MC / BMT);   // (12, 128)
  for (int ch = 0; ch < NCHUNK; ch++) {
    gather_embed_kernel<<<(MC * K_DIM / 4) / 256, 256, 0, stream>>>(x + (size_t)ch * MC, table, ebfc);
    gemm_kernel<<<g, 512, 0, stream>>>(ebfc, wcat, b_f, b_r, b_cx, projc);
    scan1_kernel<<<S_SEG * (BH / 512), 128, 0, stream>>>(projc, Pw, Qw);
    prefix_kernel<<<BH / 256, 256, 0, stream>>>(Pw, Qw, cin, c_st, segmax, hm_st,
                                                ch == 0, ch == 1);
    scan2_kernel<<<S_SEG * (BH / 512), 128, 0, stream>>>(projc, cin, segmax);
  }
  pool_final_kernel<<<BH / 256, 256, 0, stream>>>(segmax, hm_st, pooled);
  classifier_kernel<<<B_DIM * C_DIM, 64, 0, stream>>>(pooled, W_out, b_out, (float*)d_out);
}

// Round 2
// 523.480 us; speedup vs baseline: 1.0579x; 1.0579x over previous
//
#include <hip/hip_runtime.h>
#include <hip/hip_bf16.h>
#include <cstdint>
#include <cstddef>

#define T_DIM 2048
#define B_DIM 32
#define D_DIM 512
#define H_DIM 768
#define C_DIM 10
#define K_DIM D_DIM             /* 512  */
#define N_DIM (4 * H_DIM)       /* 3072 */

#define TC 1024                 /* timesteps per chunk */
#define NCHUNK (T_DIM / TC)     /* 2 */
#define MC (TC * B_DIM)         /* 32768 rows per chunk GEMM */

#define L_SEG 64                /* scan segment length */
#define S_SEG (TC / L_SEG)      /* 16 segments per chunk */
#define BH (B_DIM * H_DIM)      /* 24576 chains */

typedef __attribute__((ext_vector_type(8))) short short8;
typedef __attribute__((ext_vector_type(4))) float float4v;

__device__ inline unsigned short f2bf(float f) {
  unsigned int u = __builtin_bit_cast(unsigned int, f);
  unsigned int r = (u + 0x7FFFu + ((u >> 16) & 1u)) >> 16;
  return (unsigned short)r;
}
__device__ inline float bf2f(unsigned short s) {
  unsigned int u = ((unsigned int)s) << 16;
  return __builtin_bit_cast(float, u);
}
__device__ inline float fast_rcp(float x) { return __builtin_amdgcn_rcpf(x); }
__device__ inline float fast_exp2(float x) { return __builtin_amdgcn_exp2f(x); }
__device__ inline float sigmoid_f(float x) {
  float e = fast_exp2(-1.4426950408889634f * x);
  return fast_rcp(1.0f + e);
}
__device__ inline float tanh_f(float x) {
  float e = fast_exp2(2.885390081777927f * x);
  return 1.0f - 2.0f * fast_rcp(e + 1.0f);
}
__device__ inline void gld16(const unsigned short* g, unsigned short* l) {
  __builtin_amdgcn_global_load_lds(
      (const __attribute__((address_space(1))) void*)g,
      (__attribute__((address_space(3))) void*)l, 16, 0, 0);
}
__device__ inline unsigned int pack_bf16x2(float lo, float hi) {
  return ((unsigned int)f2bf(hi) << 16) | (unsigned int)f2bf(lo);
}

// ---------------------------------------------------------------------------
// Kernel 1: chunked embedding gather + fp32->bf16
// ---------------------------------------------------------------------------
__global__ __launch_bounds__(256) void gather_embed_kernel(
    const int* __restrict__ x_c, const float* __restrict__ table,
    unsigned short* __restrict__ ebfc) {
  int idx = blockIdx.x * 256 + threadIdx.x;
  int m = idx >> 7;
  int k4 = (idx & 127) << 2;
  int row = x_c[m];
  float4 v = *(const float4*)(table + (size_t)row * D_DIM + k4);
  ushort4 o;
  o.x = f2bf(v.x); o.y = f2bf(v.y); o.z = f2bf(v.z); o.w = f2bf(v.w);
  *(ushort4*)(ebfc + (size_t)m * D_DIM + k4) = o;
}

// ---------------------------------------------------------------------------
// Kernel 2: concat 4 weight matrices -> bf16  wcat[n][k], n: [Wx;Wf;Wr;Wcx]
// ---------------------------------------------------------------------------
__global__ __launch_bounds__(256) void convert_w_kernel(
    const float* __restrict__ Wx, const float* __restrict__ Wf,
    const float* __restrict__ Wr, const float* __restrict__ Wcx,
    unsigned short* __restrict__ wcat) {
  int idx = blockIdx.x * 256 + threadIdx.x;
  int n = idx >> 7;
  int k4 = (idx & 127) << 2;
  int mat = n / H_DIM;
  int h = n - mat * H_DIM;
  const float* src = (mat == 0) ? Wx : (mat == 1) ? Wf : (mat == 2) ? Wr : Wcx;
  float4 v = *(const float4*)(src + (size_t)h * D_DIM + k4);
  ushort4 o;
  o.x = f2bf(v.x); o.y = f2bf(v.y); o.z = f2bf(v.z); o.w = f2bf(v.w);
  *(ushort4*)(wcat + (size_t)n * D_DIM + k4) = o;
}

// ---------------------------------------------------------------------------
// Kernel 3: 128m x 256n tile, BK=32, triple-buffered, counted-vmcnt GEMM.
// Round-2 theory: round-1's 256^2/128KB version ran 1 block/CU -> the
// ~31K cy/block prologue-fetch + epilogue-store overhead had nothing to
// overlap with (6 serial blocks/CU, K only 8 tiles). This version targets
// 2 blocks/CU:
//   - 512 threads = 8 waves (4n x 2m), wave tile 64n x 64m, acc[4][4]=64 regs
//   - __launch_bounds__(512,4): cap 128 regs/wave -> 16 waves/CU = 2 blocks
//   - LDS 72KB/block (3 x 24KB k-tile buffers) -> 144KB/CU = 2 blocks fit
//   - prefetch depth 2 k-tiles; steady s_waitcnt vmcnt(3), vmcnt(0) only in
//     the peeled tail; 2 barriers/tile; setprio(1) around MFMA clusters
//   - k-chunk XOR swizzle (phys16B = logical ^ (row&3)) applied on the
//     global source addr (gload_lds dest stays linear) and on ds_read
//   - XCD-chunked bijective blockIdx swizzle (3072 blocks % 8 == 0):
//     each XCD sweeps all 12 n-panels n-fastest -> ebfc panel + 3MB wcat L2-hot
//   - epilogue unchanged in spirit: bias/sigmoid -> swizzled LDS transpose
//     (64KB, reuses buffers) -> coalesced 16B stores
// ---------------------------------------------------------------------------
#define BMT 128                 /* m rows per block (ebfc) */
#define BNT 256                 /* n rows per block (wcat) */
#define BKT 32
#define NT (K_DIM / BKT)        /* 16 */
#define BUF_SH 12288            /* shorts per k-tile buffer: A 8192 + B 4096 */

__device__ __forceinline__ float4v mfma16(short8 a, short8 b, float4v c) {
  return __builtin_amdgcn_mfma_f32_16x16x32_bf16(a, b, c, 0, 0, 0);
}

// stage A (wcat) k-tile kt into buffer buf: 256 rows x 32 shorts, 2 gld16/thread
__device__ __forceinline__ void stgA(const unsigned short* srcA, unsigned short* sm,
                                     int buf, int kt, int tid) {
  const unsigned short* s = srcA + kt * BKT;
  unsigned short* d = sm + buf * BUF_SH + tid * 8;
  gld16(s, d);
  gld16(s + (size_t)128 * K_DIM, d + 4096);
}
// stage B (ebfc) k-tile kt: 128 rows x 32 shorts, 1 gld16/thread
__device__ __forceinline__ void stgB(const unsigned short* srcB, unsigned short* sm,
                                     int buf, int kt, int tid) {
  gld16(srcB + kt * BKT, sm + buf * BUF_SH + 8192 + tid * 8);
}

template <int STG, int VMN>
__device__ __forceinline__ void tile_step(
    int u, unsigned short* sm, const unsigned short* srcA,
    const unsigned short* srcB, int tid, int aO, int bO,
    float4v (&acc)[4][4]) {
  unsigned short* c = sm + (u % 3) * BUF_SH;
  const int sbuf = (u + 2) % 3;
  short8 a[4], b[4];
#pragma unroll
  for (int f = 0; f < 4; f++) a[f] = *(const short8*)(c + aO + f * 512);
  b[0] = *(const short8*)(c + bO);
  b[1] = *(const short8*)(c + bO + 512);
  if constexpr (STG) stgA(srcA, sm, sbuf, u + 2, tid);
  __builtin_amdgcn_sched_barrier(0);
  __builtin_amdgcn_s_barrier();
  __builtin_amdgcn_s_setprio(1);
#pragma unroll
  for (int f = 0; f < 4; f++) {
    acc[f][0] = mfma16(a[f], b[0], acc[f][0]);
    acc[f][1] = mfma16(a[f], b[1], acc[f][1]);
  }
  __builtin_amdgcn_s_setprio(0);
  __builtin_amdgcn_sched_barrier(0);
  b[2] = *(const short8*)(c + bO + 1024);
  b[3] = *(const short8*)(c + bO + 1536);
  if constexpr (STG) stgB(srcB, sm, sbuf, u + 2, tid);
  __builtin_amdgcn_sched_barrier(0);
  __builtin_amdgcn_s_setprio(1);
#pragma unroll
  for (int f = 0; f < 4; f++) {
    acc[f][2] = mfma16(a[f], b[2], acc[f][2]);
    acc[f][3] = mfma16(a[f], b[3], acc[f][3]);
  }
  __builtin_amdgcn_s_setprio(0);
  __builtin_amdgcn_sched_barrier(0);
  if constexpr (VMN == 3)
    asm volatile("s_waitcnt vmcnt(3)" ::: "memory");
  else if constexpr (VMN == 0)
    asm volatile("s_waitcnt vmcnt(0)" ::: "memory");
  __builtin_amdgcn_s_barrier();
}

__global__ __launch_bounds__(512, 4) void gemm_kernel(
    const unsigned short* __restrict__ ebfc,
    const unsigned short* __restrict__ wcat,
    const float* __restrict__ b_f, const float* __restrict__ b_r,
    const float* __restrict__ b_cx,
    unsigned short* __restrict__ projc) {
  __shared__ __align__(16) unsigned short smem[36864];  // 72 KB

  const int tid = threadIdx.x;
  const int wave = tid >> 6;
  const int lane = tid & 63;
  const int quad = lane >> 4;
  const int l16 = lane & 15;
  const int wn = wave >> 1;   // 0..3: n quarter (64 rows of 256)
  const int wm = wave & 1;    // 0..1: m half (64 rows of 128)

  // XCD-chunked bijective swizzle: 3072 blocks, 384 per XCD, n-fastest.
  const int orig = blockIdx.x;
  const int swz = (orig & 7) * 384 + (orig >> 3);
  const int n_idx = swz % 12;
  const int m_idx = swz / 12;
  const int n0 = n_idx * BNT;
  const int m0 = m_idx * BMT;

  // staging source: row tid>>2, swizzled 16B k-chunk (tid&3)^(row&3)
  const int arow = tid >> 2;
  const int kchx = (tid & 3) ^ (arow & 3);
  const unsigned short* srcA = wcat + (size_t)(n0 + arow) * K_DIM + kchx * 8;
  const unsigned short* srcB = ebfc + (size_t)(m0 + arow) * K_DIM + kchx * 8;

  // ds_read lane bases (shorts): row*32 + swizzled chunk
  const int xr = (quad ^ (l16 & 3)) * 8;
  const int aO = (wn * 64 + l16) * 32 + xr;
  const int bO = 8192 + (wm * 64 + l16) * 32 + xr;

  float4v acc[4][4] = {};

  // ---- prologue: stage tiles 0 and 1; wait tile 0 (vmcnt 3) ----
  stgA(srcA, smem, 0, 0, tid);
  stgB(srcB, smem, 0, 0, tid);
  stgA(srcA, smem, 1, 1, tid);
  stgB(srcB, smem, 1, 1, tid);
  asm volatile("s_waitcnt vmcnt(3)" ::: "memory");
  __builtin_amdgcn_s_barrier();

  // ---- main loop: stage u+2 during u; steady vmcnt(3) ----
#pragma unroll
  for (int u = 0; u < NT - 2; u++)
    tile_step<1, 3>(u, smem, srcA, srcB, tid, aO, bO, acc);
  tile_step<0, 0>(NT - 2, smem, srcA, srcB, tid, aO, bO, acc);
  tile_step<0, -1>(NT - 1, smem, srcA, srcB, tid, aO, bO, acc);

  // ---- epilogue: bias/sigmoid -> swizzled LDS transpose -> 16B stores ----
  __syncthreads();
  int mat = n0 / H_DIM;                      // uniform per block (768 = 3*256)
  int hb = n0 - mat * H_DIM;                 // 0, 256, or 512
  size_t matBase = (size_t)mat * MC * H_DIM;
  const float* bias = (mat == 1) ? b_f : (mat == 2) ? b_r : b_cx;
#pragma unroll
  for (int f = 0; f < 4; f++) {
    int hl = wn * 64 + f * 16 + quad * 4;    // local h (0..255), 4 consecutive
    float4 bv;
    if (mat == 0) { bv.x = bv.y = bv.z = bv.w = 0.0f; }
    else          { bv = *(const float4*)(bias + hb + hl); }
#pragma unroll
    for (int g = 0; g < 4; g++) {
      int ml = wm * 64 + g * 16 + l16;       // local m (0..127)
      float v0 = acc[f][g][0] + bv.x;
      float v1 = acc[f][g][1] + bv.y;
      float v2 = acc[f][g][2] + bv.z;
      float v3 = acc[f][g][3] + bv.w;
      if (mat == 1 || mat == 2) {
        v0 = sigmoid_f(v0); v1 = sigmoid_f(v1);
        v2 = sigmoid_f(v2); v3 = sigmoid_f(v3);
      }
      uint2 pk;
      pk.x = pack_bf16x2(v0, v1);
      pk.y = pack_bf16x2(v2, v3);
      int log8 = hl >> 2;                    // 8-byte chunk of the h row
      int phys8 = log8 ^ ((ml & 7) << 1);    // even XOR: 16B pairs adjacent
      *(uint2*)(smem + ml * 256 + phys8 * 4) = pk;
    }
  }
  __syncthreads();
#pragma unroll
  for (int it = 0; it < 8; it++) {
    int idx = it * 512 + tid;
    int ml = idx >> 5;                       // local m
    int c16 = idx & 31;                      // logical 16B chunk of h
    int phys16 = c16 ^ (ml & 7);
    short8 v = *(const short8*)(smem + ml * 256 + phys16 * 8);
    *(short8*)(projc + matBase + (size_t)(m0 + ml) * H_DIM + hb + c16 * 8) = v;
  }
}

// ---------------------------------------------------------------------------
// Kernel 4a (scan1): per-segment summaries P = prod f, Q = c_out given c_in=0.
// ---------------------------------------------------------------------------
__global__ __launch_bounds__(128) void scan1_kernel(
    const unsigned short* __restrict__ projc,
    float* __restrict__ Pw, float* __restrict__ Qw) {
  int blk = blockIdx.x;
  int seg = blk / (BH / 512);
  int q   = blk % (BH / 512);
  int e4  = (q * 128 + threadIdx.x) * 4;
  const size_t mstr = (size_t)MC * H_DIM;
  size_t idx0 = (size_t)(seg * L_SEG) * BH + e4;
  float p0 = 1.f, p1 = 1.f, p2 = 1.f, p3 = 1.f;
  float c0 = 0.f, c1 = 0.f, c2 = 0.f, c3 = 0.f;
#pragma unroll 4
  for (int t = 0; t < L_SEG; t++) {
    size_t id = idx0 + (size_t)t * BH;
    ushort4 xp = *(const ushort4*)(projc + id);
    ushort4 ff = *(const ushort4*)(projc + mstr + id);
    float f0 = bf2f(ff.x), f1 = bf2f(ff.y), f2 = bf2f(ff.z), f3 = bf2f(ff.w);
    c0 = fmaf(f0, c0 - bf2f(xp.x), bf2f(xp.x));
    c1 = fmaf(f1, c1 - bf2f(xp.y), bf2f(xp.y));
    c2 = fmaf(f2, c2 - bf2f(xp.z), bf2f(xp.z));
    c3 = fmaf(f3, c3 - bf2f(xp.w), bf2f(xp.w));
    p0 *= f0; p1 *= f1; p2 *= f2; p3 *= f3;
  }
  int o = seg * BH + e4;
  *(float4*)(Pw + o) = make_float4(p0, p1, p2, p3);
  *(float4*)(Qw + o) = make_float4(c0, c1, c2, c3);
}

// ---------------------------------------------------------------------------
// Kernel 4b (prefix): chain segments exactly: c_out = P*c_in + Q.
// ---------------------------------------------------------------------------
__global__ __launch_bounds__(256) void prefix_kernel(
    const float* __restrict__ Pw, const float* __restrict__ Qw,
    float* __restrict__ cin, float* __restrict__ c_state,
    const float* __restrict__ segmax, float* __restrict__ hm_state,
    int first, int hm_init) {
  int gid = blockIdx.x * 256 + threadIdx.x;
  float c = first ? 0.f : c_state[gid];
#pragma unroll
  for (int s = 0; s < S_SEG; s++) {
    cin[s * BH + gid] = c;
    c = fmaf(Pw[s * BH + gid], c, Qw[s * BH + gid]);
  }
  c_state[gid] = c;
  if (!first) {
    float m = segmax[gid];
#pragma unroll
    for (int s = 1; s < S_SEG; s++) m = fmaxf(m, segmax[s * BH + gid]);
    hm_state[gid] = hm_init ? m : fmaxf(hm_state[gid], m);
  }
}

// ---------------------------------------------------------------------------
// Kernel 4c (scan2): replay each segment from true c_in; h + segment max.
// ---------------------------------------------------------------------------
__global__ __launch_bounds__(128) void scan2_kernel(
    const unsigned short* __restrict__ projc,
    const float* __restrict__ cin, float* __restrict__ segmax) {
  int blk = blockIdx.x;
  int seg = blk / (BH / 512);
  int q   = blk % (BH / 512);
  int e4  = (q * 128 + threadIdx.x) * 4;
  const size_t mstr = (size_t)MC * H_DIM;
  size_t idx0 = (size_t)(seg * L_SEG) * BH + e4;
  int o = seg * BH + e4;
  float4 cv = *(const float4*)(cin + o);
  float c0 = cv.x, c1 = cv.y, c2 = cv.z, c3 = cv.w;
  float m0 = -1e30f, m1 = -1e30f, m2 = -1e30f, m3 = -1e30f;
#pragma unroll 2
  for (int t = 0; t < L_SEG; t++) {
    size_t id = idx0 + (size_t)t * BH;
    ushort4 xp = *(const ushort4*)(projc + id);
    ushort4 ff = *(const ushort4*)(projc + mstr + id);
    ushort4 rr = *(const ushort4*)(projc + 2 * mstr + id);
    ushort4 cx = *(const ushort4*)(projc + 3 * mstr + id);
    c0 = fmaf(bf2f(ff.x), c0 - bf2f(xp.x), bf2f(xp.x));
    c1 = fmaf(bf2f(ff.y), c1 - bf2f(xp.y), bf2f(xp.y));
    c2 = fmaf(bf2f(ff.z), c2 - bf2f(xp.z), bf2f(xp.z));
    c3 = fmaf(bf2f(ff.w), c3 - bf2f(xp.w), bf2f(xp.w));
    float h0 = fmaf(bf2f(rr.x), tanh_f(c0) - bf2f(cx.x), bf2f(cx.x));
    float h1 = fmaf(bf2f(rr.y), tanh_f(c1) - bf2f(cx.y), bf2f(cx.y));
    float h2 = fmaf(bf2f(rr.z), tanh_f(c2) - bf2f(cx.z), bf2f(cx.z));
    float h3 = fmaf(bf2f(rr.w), tanh_f(c3) - bf2f(cx.w), bf2f(cx.w));
    m0 = fmaxf(m0, h0); m1 = fmaxf(m1, h1);
    m2 = fmaxf(m2, h2); m3 = fmaxf(m3, h3);
  }
  *(float4*)(segmax + o) = make_float4(m0, m1, m2, m3);
}

// ---------------------------------------------------------------------------
// Kernel 4d: final pool = tanh(tanh(max(hm_state, last chunk's segmax)))
// ---------------------------------------------------------------------------
__global__ __launch_bounds__(256) void pool_final_kernel(
    const float* __restrict__ segmax, const float* __restrict__ hm_state,
    float* __restrict__ pooled) {
  int gid = blockIdx.x * 256 + threadIdx.x;
  float m = hm_state[gid];
#pragma unroll
  for (int s = 0; s < S_SEG; s++) m = fmaxf(m, segmax[s * BH + gid]);
  pooled[gid] = tanh_f(tanh_f(m));
}

// ---------------------------------------------------------------------------
// Kernel 5: classifier  logit[b][c] = pooled[b]·W_out[c] + b_out[c]
// ---------------------------------------------------------------------------
__global__ __launch_bounds__(64) void classifier_kernel(
    const float* __restrict__ pooled, const float* __restrict__ W_out,
    const float* __restrict__ b_out, float* __restrict__ out) {
  int b = blockIdx.x / C_DIM;
  int c = blockIdx.x % C_DIM;
  int lane = threadIdx.x;
  float s = 0.0f;
#pragma unroll
  for (int i = 0; i < H_DIM / 64; i++) {
    int h = i * 64 + lane;
    s += pooled[(size_t)b * H_DIM + h] * W_out[(size_t)c * H_DIM + h];
  }
#pragma unroll
  for (int off = 32; off; off >>= 1) s += __shfl_down(s, off, 64);
  if (lane == 0) out[b * C_DIM + c] = s + b_out[c];
}

// ---------------------------------------------------------------------------
extern "C" void kernel_launch(void* const* d_in, const int* in_sizes, int n_in,
                              void* d_out, int out_size, void* d_ws, size_t ws_size,
                              hipStream_t stream) {
  const int*   x     = (const int*)d_in[0];
  const float* table = (const float*)d_in[1];
  const float* W_x   = (const float*)d_in[2];
  const float* W_f   = (const float*)d_in[3];
  const float* b_f   = (const float*)d_in[4];
  const float* W_r   = (const float*)d_in[5];
  const float* b_r   = (const float*)d_in[6];
  const float* W_cx  = (const float*)d_in[7];
  const float* b_cx  = (const float*)d_in[8];
  const float* W_out = (const float*)d_in[9];
  const float* b_out = (const float*)d_in[10];

  // workspace layout (~245 MB; ws_size ~411 MB per harness fill size)
  char* ws = (char*)d_ws;
  size_t off = 0;
  unsigned short* wcat  = (unsigned short*)(ws + off); off += (size_t)N_DIM * K_DIM * 2;
  unsigned short* ebfc  = (unsigned short*)(ws + off); off += (size_t)MC * K_DIM * 2;
  unsigned short* projc = (unsigned short*)(ws + off); off += (size_t)4 * MC * H_DIM * 2;
  float* Pw     = (float*)(ws + off); off += (size_t)S_SEG * BH * 4;
  float* Qw     = (float*)(ws + off); off += (size_t)S_SEG * BH * 4;
  float* cin    = (float*)(ws + off); off += (size_t)S_SEG * BH * 4;
  float* segmax = (float*)(ws + off); off += (size_t)S_SEG * BH * 4;
  float* c_st   = (float*)(ws + off); off += (size_t)BH * 4;
  float* hm_st  = (float*)(ws + off); off += (size_t)BH * 4;
  float* pooled = (float*)(ws + off); off += (size_t)BH * 4;

  convert_w_kernel<<<(N_DIM * K_DIM / 4) / 256, 256, 0, stream>>>(W_x, W_f, W_r, W_cx, wcat);

  for (int ch = 0; ch < NCHUNK; ch++) {
    gather_embed_kernel<<<(MC * K_DIM / 4) / 256, 256, 0, stream>>>(x + (size_t)ch * MC, table, ebfc);
    gemm_kernel<<<(N_DIM / BNT) * (MC / BMT), 512, 0, stream>>>(ebfc, wcat, b_f, b_r, b_cx, projc);
    scan1_kernel<<<S_SEG * (BH / 512), 128, 0, stream>>>(projc, Pw, Qw);
    prefix_kernel<<<BH / 256, 256, 0, stream>>>(Pw, Qw, cin, c_st, segmax, hm_st,
                                                ch == 0, ch == 1);
    scan2_kernel<<<S_SEG * (BH / 512), 128, 0, stream>>>(projc, cin, segmax);
  }
  pool_final_kernel<<<BH / 256, 256, 0, stream>>>(segmax, hm_st, pooled);
  classifier_kernel<<<B_DIM * C_DIM, 64, 0, stream>>>(pooled, W_out, b_out, (float*)d_out);
}

// Round 3
// 522.289 us; speedup vs baseline: 1.0603x; 1.0023x over previous
//
#include <hip/hip_runtime.h>
#include <hip/hip_bf16.h>
#include <cstdint>
#include <cstddef>

#define T_DIM 2048
#define B_DIM 32
#define D_DIM 512
#define H_DIM 768
#define C_DIM 10
#define K_DIM D_DIM             /* 512  */
#define N_DIM (4 * H_DIM)       /* 3072 */

#define TC 1024                 /* timesteps per chunk */
#define NCHUNK (T_DIM / TC)     /* 2 */
#define MC (TC * B_DIM)         /* 32768 rows per chunk GEMM */

#define L_SEG 64                /* scan segment length */
#define S_SEG (TC / L_SEG)      /* 16 segments per chunk */
#define BH (B_DIM * H_DIM)      /* 24576 chains */

typedef __attribute__((ext_vector_type(8))) short short8;
typedef __attribute__((ext_vector_type(4))) float float4v;

__device__ inline unsigned short f2bf(float f) {
  unsigned int u = __builtin_bit_cast(unsigned int, f);
  unsigned int r = (u + 0x7FFFu + ((u >> 16) & 1u)) >> 16;
  return (unsigned short)r;
}
__device__ inline float bf2f(unsigned short s) {
  unsigned int u = ((unsigned int)s) << 16;
  return __builtin_bit_cast(float, u);
}
__device__ inline float fast_rcp(float x) { return __builtin_amdgcn_rcpf(x); }
__device__ inline float fast_exp2(float x) { return __builtin_amdgcn_exp2f(x); }
__device__ inline float sigmoid_f(float x) {
  float e = fast_exp2(-1.4426950408889634f * x);
  return fast_rcp(1.0f + e);
}
__device__ inline float tanh_f(float x) {
  float e = fast_exp2(2.885390081777927f * x);
  return 1.0f - 2.0f * fast_rcp(e + 1.0f);
}
__device__ inline void gld16(const unsigned short* g, unsigned short* l) {
  __builtin_amdgcn_global_load_lds(
      (const __attribute__((address_space(1))) void*)g,
      (__attribute__((address_space(3))) void*)l, 16, 0, 0);
}
__device__ inline unsigned int pack_bf16x2(float lo, float hi) {
  return ((unsigned int)f2bf(hi) << 16) | (unsigned int)f2bf(lo);
}

// ---------------------------------------------------------------------------
// Kernel 1: chunked embedding gather + fp32->bf16
// ---------------------------------------------------------------------------
__global__ __launch_bounds__(256) void gather_embed_kernel(
    const int* __restrict__ x_c, const float* __restrict__ table,
    unsigned short* __restrict__ ebfc) {
  int idx = blockIdx.x * 256 + threadIdx.x;
  int m = idx >> 7;
  int k4 = (idx & 127) << 2;
  int row = x_c[m];
  float4 v = *(const float4*)(table + (size_t)row * D_DIM + k4);
  ushort4 o;
  o.x = f2bf(v.x); o.y = f2bf(v.y); o.z = f2bf(v.z); o.w = f2bf(v.w);
  *(ushort4*)(ebfc + (size_t)m * D_DIM + k4) = o;
}

// ---------------------------------------------------------------------------
// Kernel 2: concat 4 weight matrices -> bf16  wcat[n][k], n: [Wx;Wf;Wr;Wcx]
// ---------------------------------------------------------------------------
__global__ __launch_bounds__(256) void convert_w_kernel(
    const float* __restrict__ Wx, const float* __restrict__ Wf,
    const float* __restrict__ Wr, const float* __restrict__ Wcx,
    unsigned short* __restrict__ wcat) {
  int idx = blockIdx.x * 256 + threadIdx.x;
  int n = idx >> 7;
  int k4 = (idx & 127) << 2;
  int mat = n / H_DIM;
  int h = n - mat * H_DIM;
  const float* src = (mat == 0) ? Wx : (mat == 1) ? Wf : (mat == 2) ? Wr : Wcx;
  float4 v = *(const float4*)(src + (size_t)h * D_DIM + k4);
  ushort4 o;
  o.x = f2bf(v.x); o.y = f2bf(v.y); o.z = f2bf(v.z); o.w = f2bf(v.w);
  *(ushort4*)(wcat + (size_t)n * D_DIM + k4) = o;
}

// ---------------------------------------------------------------------------
// Kernel 3: 128m x 256n tile, BK=32, triple-buffered, counted-vmcnt GEMM.
// Round-3 fix: round-2 regressed the k-chunk XOR swizzle to (row&3), which
// puts rows {0,4,8,12} of each quad on the SAME 16B bank slot (same parity,
// same chunk) -> 4-way conflicts on every ds_read_b128 (SQ_LDS_BANK_CONFLICT
// 1.57M -> 14.16M, ~17% of kernel cycles). The correct involution is
// ((row>>1)&3): bank slot = (row&1)*4 + chunk walks all 8 slots with exactly
// 2 lanes each (2-way = free, m136). Applied identically on the staging
// SOURCE address (gload_lds dest stays linear) and the ds_read chunk.
// Everything else unchanged from round 2 (2 blocks/CU, vmcnt(3), setprio,
// XCD-chunked bijective swizzle).
// ---------------------------------------------------------------------------
#define BMT 128                 /* m rows per block (ebfc) */
#define BNT 256                 /* n rows per block (wcat) */
#define BKT 32
#define NT (K_DIM / BKT)        /* 16 */
#define BUF_SH 12288            /* shorts per k-tile buffer: A 8192 + B 4096 */

__device__ __forceinline__ float4v mfma16(short8 a, short8 b, float4v c) {
  return __builtin_amdgcn_mfma_f32_16x16x32_bf16(a, b, c, 0, 0, 0);
}

// stage A (wcat) k-tile kt into buffer buf: 256 rows x 32 shorts, 2 gld16/thread
__device__ __forceinline__ void stgA(const unsigned short* srcA, unsigned short* sm,
                                     int buf, int kt, int tid) {
  const unsigned short* s = srcA + kt * BKT;
  unsigned short* d = sm + buf * BUF_SH + tid * 8;
  gld16(s, d);
  gld16(s + (size_t)128 * K_DIM, d + 4096);
}
// stage B (ebfc) k-tile kt: 128 rows x 32 shorts, 1 gld16/thread
__device__ __forceinline__ void stgB(const unsigned short* srcB, unsigned short* sm,
                                     int buf, int kt, int tid) {
  gld16(srcB + kt * BKT, sm + buf * BUF_SH + 8192 + tid * 8);
}

template <int STG, int VMN>
__device__ __forceinline__ void tile_step(
    int u, unsigned short* sm, const unsigned short* srcA,
    const unsigned short* srcB, int tid, int aO, int bO,
    float4v (&acc)[4][4]) {
  unsigned short* c = sm + (u % 3) * BUF_SH;
  const int sbuf = (u + 2) % 3;
  short8 a[4], b[4];
#pragma unroll
  for (int f = 0; f < 4; f++) a[f] = *(const short8*)(c + aO + f * 512);
  b[0] = *(const short8*)(c + bO);
  b[1] = *(const short8*)(c + bO + 512);
  if constexpr (STG) stgA(srcA, sm, sbuf, u + 2, tid);
  __builtin_amdgcn_sched_barrier(0);
  __builtin_amdgcn_s_barrier();
  __builtin_amdgcn_s_setprio(1);
#pragma unroll
  for (int f = 0; f < 4; f++) {
    acc[f][0] = mfma16(a[f], b[0], acc[f][0]);
    acc[f][1] = mfma16(a[f], b[1], acc[f][1]);
  }
  __builtin_amdgcn_s_setprio(0);
  __builtin_amdgcn_sched_barrier(0);
  b[2] = *(const short8*)(c + bO + 1024);
  b[3] = *(const short8*)(c + bO + 1536);
  if constexpr (STG) stgB(srcB, sm, sbuf, u + 2, tid);
  __builtin_amdgcn_sched_barrier(0);
  __builtin_amdgcn_s_setprio(1);
#pragma unroll
  for (int f = 0; f < 4; f++) {
    acc[f][2] = mfma16(a[f], b[2], acc[f][2]);
    acc[f][3] = mfma16(a[f], b[3], acc[f][3]);
  }
  __builtin_amdgcn_s_setprio(0);
  __builtin_amdgcn_sched_barrier(0);
  if constexpr (VMN == 3)
    asm volatile("s_waitcnt vmcnt(3)" ::: "memory");
  else if constexpr (VMN == 0)
    asm volatile("s_waitcnt vmcnt(0)" ::: "memory");
  __builtin_amdgcn_s_barrier();
}

__global__ __launch_bounds__(512, 4) void gemm_kernel(
    const unsigned short* __restrict__ ebfc,
    const unsigned short* __restrict__ wcat,
    const float* __restrict__ b_f, const float* __restrict__ b_r,
    const float* __restrict__ b_cx,
    unsigned short* __restrict__ projc) {
  __shared__ __align__(16) unsigned short smem[36864];  // 72 KB

  const int tid = threadIdx.x;
  const int wave = tid >> 6;
  const int lane = tid & 63;
  const int quad = lane >> 4;
  const int l16 = lane & 15;
  const int wn = wave >> 1;   // 0..3: n quarter (64 rows of 256)
  const int wm = wave & 1;    // 0..1: m half (64 rows of 128)

  // XCD-chunked bijective swizzle: 3072 blocks, 384 per XCD, n-fastest.
  const int orig = blockIdx.x;
  const int swz = (orig & 7) * 384 + (orig >> 3);
  const int n_idx = swz % 12;
  const int m_idx = swz / 12;
  const int n0 = n_idx * BNT;
  const int m0 = m_idx * BMT;

  // staging source: row tid>>2, swizzled 16B k-chunk (tid&3)^((row>>1)&3)
  const int arow = tid >> 2;
  const int kchx = (tid & 3) ^ ((arow >> 1) & 3);
  const unsigned short* srcA = wcat + (size_t)(n0 + arow) * K_DIM + kchx * 8;
  const unsigned short* srcB = ebfc + (size_t)(m0 + arow) * K_DIM + kchx * 8;

  // ds_read lane bases (shorts): row*32 + swizzled chunk, row = w*64+l16
  // phys chunk = quad ^ ((row>>1)&3) = quad ^ ((l16>>1)&3)  (w*64 even in bit1? 64 rows -> (row>>1)&3 depends on l16 only since base is mult of 64: (64w+l16)>>1 = 32w + (l16>>1); &3 of 32w = 0)
  const int xr = (quad ^ ((l16 >> 1) & 3)) * 8;
  const int aO = (wn * 64 + l16) * 32 + xr;
  const int bO = 8192 + (wm * 64 + l16) * 32 + xr;

  float4v acc[4][4] = {};

  // ---- prologue: stage tiles 0 and 1; wait tile 0 (vmcnt 3) ----
  stgA(srcA, smem, 0, 0, tid);
  stgB(srcB, smem, 0, 0, tid);
  stgA(srcA, smem, 1, 1, tid);
  stgB(srcB, smem, 1, 1, tid);
  asm volatile("s_waitcnt vmcnt(3)" ::: "memory");
  __builtin_amdgcn_s_barrier();

  // ---- main loop: stage u+2 during u; steady vmcnt(3) ----
#pragma unroll
  for (int u = 0; u < NT - 2; u++)
    tile_step<1, 3>(u, smem, srcA, srcB, tid, aO, bO, acc);
  tile_step<0, 0>(NT - 2, smem, srcA, srcB, tid, aO, bO, acc);
  tile_step<0, -1>(NT - 1, smem, srcA, srcB, tid, aO, bO, acc);

  // ---- epilogue: bias/sigmoid -> swizzled LDS transpose -> 16B stores ----
  __syncthreads();
  int mat = n0 / H_DIM;                      // uniform per block (768 = 3*256)
  int hb = n0 - mat * H_DIM;                 // 0, 256, or 512
  size_t matBase = (size_t)mat * MC * H_DIM;
  const float* bias = (mat == 1) ? b_f : (mat == 2) ? b_r : b_cx;
#pragma unroll
  for (int f = 0; f < 4; f++) {
    int hl = wn * 64 + f * 16 + quad * 4;    // local h (0..255), 4 consecutive
    float4 bv;
    if (mat == 0) { bv.x = bv.y = bv.z = bv.w = 0.0f; }
    else          { bv = *(const float4*)(bias + hb + hl); }
#pragma unroll
    for (int g = 0; g < 4; g++) {
      int ml = wm * 64 + g * 16 + l16;       // local m (0..127)
      float v0 = acc[f][g][0] + bv.x;
      float v1 = acc[f][g][1] + bv.y;
      float v2 = acc[f][g][2] + bv.z;
      float v3 = acc[f][g][3] + bv.w;
      if (mat == 1 || mat == 2) {
        v0 = sigmoid_f(v0); v1 = sigmoid_f(v1);
        v2 = sigmoid_f(v2); v3 = sigmoid_f(v3);
      }
      uint2 pk;
      pk.x = pack_bf16x2(v0, v1);
      pk.y = pack_bf16x2(v2, v3);
      int log8 = hl >> 2;                    // 8-byte chunk of the h row
      int phys8 = log8 ^ ((ml & 7) << 1);    // even XOR: 16B pairs adjacent
      *(uint2*)(smem + ml * 256 + phys8 * 4) = pk;
    }
  }
  __syncthreads();
#pragma unroll
  for (int it = 0; it < 8; it++) {
    int idx = it * 512 + tid;
    int ml = idx >> 5;                       // local m
    int c16 = idx & 31;                      // logical 16B chunk of h
    int phys16 = c16 ^ (ml & 7);
    short8 v = *(const short8*)(smem + ml * 256 + phys16 * 8);
    *(short8*)(projc + matBase + (size_t)(m0 + ml) * H_DIM + hb + c16 * 8) = v;
  }
}

// ---------------------------------------------------------------------------
// Kernel 4a (scan1): per-segment summaries P = prod f, Q = c_out given c_in=0.
// ---------------------------------------------------------------------------
__global__ __launch_bounds__(128) void scan1_kernel(
    const unsigned short* __restrict__ projc,
    float* __restrict__ Pw, float* __restrict__ Qw) {
  int blk = blockIdx.x;
  int seg = blk / (BH / 512);
  int q   = blk % (BH / 512);
  int e4  = (q * 128 + threadIdx.x) * 4;
  const size_t mstr = (size_t)MC * H_DIM;
  size_t idx0 = (size_t)(seg * L_SEG) * BH + e4;
  float p0 = 1.f, p1 = 1.f, p2 = 1.f, p3 = 1.f;
  float c0 = 0.f, c1 = 0.f, c2 = 0.f, c3 = 0.f;
#pragma unroll 4
  for (int t = 0; t < L_SEG; t++) {
    size_t id = idx0 + (size_t)t * BH;
    ushort4 xp = *(const ushort4*)(projc + id);
    ushort4 ff = *(const ushort4*)(projc + mstr + id);
    float f0 = bf2f(ff.x), f1 = bf2f(ff.y), f2 = bf2f(ff.z), f3 = bf2f(ff.w);
    c0 = fmaf(f0, c0 - bf2f(xp.x), bf2f(xp.x));
    c1 = fmaf(f1, c1 - bf2f(xp.y), bf2f(xp.y));
    c2 = fmaf(f2, c2 - bf2f(xp.z), bf2f(xp.z));
    c3 = fmaf(f3, c3 - bf2f(xp.w), bf2f(xp.w));
    p0 *= f0; p1 *= f1; p2 *= f2; p3 *= f3;
  }
  int o = seg * BH + e4;
  *(float4*)(Pw + o) = make_float4(p0, p1, p2, p3);
  *(float4*)(Qw + o) = make_float4(c0, c1, c2, c3);
}

// ---------------------------------------------------------------------------
// Kernel 4b (prefix): chain segments exactly: c_out = P*c_in + Q.
// ---------------------------------------------------------------------------
__global__ __launch_bounds__(256) void prefix_kernel(
    const float* __restrict__ Pw, const float* __restrict__ Qw,
    float* __restrict__ cin, float* __restrict__ c_state,
    const float* __restrict__ segmax, float* __restrict__ hm_state,
    int first, int hm_init) {
  int gid = blockIdx.x * 256 + threadIdx.x;
  float c = first ? 0.f : c_state[gid];
#pragma unroll
  for (int s = 0; s < S_SEG; s++) {
    cin[s * BH + gid] = c;
    c = fmaf(Pw[s * BH + gid], c, Qw[s * BH + gid]);
  }
  c_state[gid] = c;
  if (!first) {
    float m = segmax[gid];
#pragma unroll
    for (int s = 1; s < S_SEG; s++) m = fmaxf(m, segmax[s * BH + gid]);
    hm_state[gid] = hm_init ? m : fmaxf(hm_state[gid], m);
  }
}

// ---------------------------------------------------------------------------
// Kernel 4c (scan2): replay each segment from true c_in; h + segment max.
// ---------------------------------------------------------------------------
__global__ __launch_bounds__(128) void scan2_kernel(
    const unsigned short* __restrict__ projc,
    const float* __restrict__ cin, float* __restrict__ segmax) {
  int blk = blockIdx.x;
  int seg = blk / (BH / 512);
  int q   = blk % (BH / 512);
  int e4  = (q * 128 + threadIdx.x) * 4;
  const size_t mstr = (size_t)MC * H_DIM;
  size_t idx0 = (size_t)(seg * L_SEG) * BH + e4;
  int o = seg * BH + e4;
  float4 cv = *(const float4*)(cin + o);
  float c0 = cv.x, c1 = cv.y, c2 = cv.z, c3 = cv.w;
  float m0 = -1e30f, m1 = -1e30f, m2 = -1e30f, m3 = -1e30f;
#pragma unroll 2
  for (int t = 0; t < L_SEG; t++) {
    size_t id = idx0 + (size_t)t * BH;
    ushort4 xp = *(const ushort4*)(projc + id);
    ushort4 ff = *(const ushort4*)(projc + mstr + id);
    ushort4 rr = *(const ushort4*)(projc + 2 * mstr + id);
    ushort4 cx = *(const ushort4*)(projc + 3 * mstr + id);
    c0 = fmaf(bf2f(ff.x), c0 - bf2f(xp.x), bf2f(xp.x));
    c1 = fmaf(bf2f(ff.y), c1 - bf2f(xp.y), bf2f(xp.y));
    c2 = fmaf(bf2f(ff.z), c2 - bf2f(xp.z), bf2f(xp.z));
    c3 = fmaf(bf2f(ff.w), c3 - bf2f(xp.w), bf2f(xp.w));
    float h0 = fmaf(bf2f(rr.x), tanh_f(c0) - bf2f(cx.x), bf2f(cx.x));
    float h1 = fmaf(bf2f(rr.y), tanh_f(c1) - bf2f(cx.y), bf2f(cx.y));
    float h2 = fmaf(bf2f(rr.z), tanh_f(c2) - bf2f(cx.z), bf2f(cx.z));
    float h3 = fmaf(bf2f(rr.w), tanh_f(c3) - bf2f(cx.w), bf2f(cx.w));
    m0 = fmaxf(m0, h0); m1 = fmaxf(m1, h1);
    m2 = fmaxf(m2, h2); m3 = fmaxf(m3, h3);
  }
  *(float4*)(segmax + o) = make_float4(m0, m1, m2, m3);
}

// ---------------------------------------------------------------------------
// Kernel 4d: final pool = tanh(tanh(max(hm_state, last chunk's segmax)))
// ---------------------------------------------------------------------------
__global__ __launch_bounds__(256) void pool_final_kernel(
    const float* __restrict__ segmax, const float* __restrict__ hm_state,
    float* __restrict__ pooled) {
  int gid = blockIdx.x * 256 + threadIdx.x;
  float m = hm_state[gid];
#pragma unroll
  for (int s = 0; s < S_SEG; s++) m = fmaxf(m, segmax[s * BH + gid]);
  pooled[gid] = tanh_f(tanh_f(m));
}

// ---------------------------------------------------------------------------
// Kernel 5: classifier  logit[b][c] = pooled[b]·W_out[c] + b_out[c]
// ---------------------------------------------------------------------------
__global__ __launch_bounds__(64) void classifier_kernel(
    const float* __restrict__ pooled, const float* __restrict__ W_out,
    const float* __restrict__ b_out, float* __restrict__ out) {
  int b = blockIdx.x / C_DIM;
  int c = blockIdx.x % C_DIM;
  int lane = threadIdx.x;
  float s = 0.0f;
#pragma unroll
  for (int i = 0; i < H_DIM / 64; i++) {
    int h = i * 64 + lane;
    s += pooled[(size_t)b * H_DIM + h] * W_out[(size_t)c * H_DIM + h];
  }
#pragma unroll
  for (int off = 32; off; off >>= 1) s += __shfl_down(s, off, 64);
  if (lane == 0) out[b * C_DIM + c] = s + b_out[c];
}

// ---------------------------------------------------------------------------
extern "C" void kernel_launch(void* const* d_in, const int* in_sizes, int n_in,
                              void* d_out, int out_size, void* d_ws, size_t ws_size,
                              hipStream_t stream) {
  const int*   x     = (const int*)d_in[0];
  const float* table = (const float*)d_in[1];
  const float* W_x   = (const float*)d_in[2];
  const float* W_f   = (const float*)d_in[3];
  const float* b_f   = (const float*)d_in[4];
  const float* W_r   = (const float*)d_in[5];
  const float* b_r   = (const float*)d_in[6];
  const float* W_cx  = (const float*)d_in[7];
  const float* b_cx  = (const float*)d_in[8];
  const float* W_out = (const float*)d_in[9];
  const float* b_out = (const float*)d_in[10];

  // workspace layout (~245 MB; ws_size ~411 MB per harness fill size)
  char* ws = (char*)d_ws;
  size_t off = 0;
  unsigned short* wcat  = (unsigned short*)(ws + off); off += (size_t)N_DIM * K_DIM * 2;
  unsigned short* ebfc  = (unsigned short*)(ws + off); off += (size_t)MC * K_DIM * 2;
  unsigned short* projc = (unsigned short*)(ws + off); off += (size_t)4 * MC * H_DIM * 2;
  float* Pw     = (float*)(ws + off); off += (size_t)S_SEG * BH * 4;
  float* Qw     = (float*)(ws + off); off += (size_t)S_SEG * BH * 4;
  float* cin    = (float*)(ws + off); off += (size_t)S_SEG * BH * 4;
  float* segmax = (float*)(ws + off); off += (size_t)S_SEG * BH * 4;
  float* c_st   = (float*)(ws + off); off += (size_t)BH * 4;
  float* hm_st  = (float*)(ws + off); off += (size_t)BH * 4;
  float* pooled = (float*)(ws + off); off += (size_t)BH * 4;

  convert_w_kernel<<<(N_DIM * K_DIM / 4) / 256, 256, 0, stream>>>(W_x, W_f, W_r, W_cx, wcat);

  for (int ch = 0; ch < NCHUNK; ch++) {
    gather_embed_kernel<<<(MC * K_DIM / 4) / 256, 256, 0, stream>>>(x + (size_t)ch * MC, table, ebfc);
    gemm_kernel<<<(N_DIM / BNT) * (MC / BMT), 512, 0, stream>>>(ebfc, wcat, b_f, b_r, b_cx, projc);
    scan1_kernel<<<S_SEG * (BH / 512), 128, 0, stream>>>(projc, Pw, Qw);
    prefix_kernel<<<BH / 256, 256, 0, stream>>>(Pw, Qw, cin, c_st, segmax, hm_st,
                                                ch == 0, ch == 1);
    scan2_kernel<<<S_SEG * (BH / 512), 128, 0, stream>>>(projc, cin, segmax);
  }
  pool_final_kernel<<<BH / 256, 256, 0, stream>>>(segmax, hm_st, pooled);
  classifier_kernel<<<B_DIM * C_DIM, 64, 0, stream>>>(pooled, W_out, b_out, (float*)d_out);
}